// Round 10
// baseline (395.369 us; speedup 1.0000x reference)
//
#include <hip/hip_runtime.h>

#define N_NODES 100000
#define N_EDGES 1600000
#define D 128
#define NB 196              // buckets of 512 nodes: 196*512 = 100352 >= N_NODES
#define EPT 10              // edges per thread
#define CHUNK 2560          // 256 threads * EPT
#define BIN_BLOCKS 625      // 625 * 2560 = 1,600,000 exactly
#define CVT_X_BLOCKS 6250   // 6250*256*8 = 12.8M elements
#define ZROW N_NODES        // index of the zeroed padding row in x_bf
#define PBK 13312           // per-bucket fixed srcs region (max ~8600 edges + 512*7 pad)

typedef __bf16 bf16x8 __attribute__((ext_vector_type(8)));
typedef float f32x4 __attribute__((ext_vector_type(4)));

__device__ __forceinline__ unsigned f2bf(float f) {
    unsigned u = __float_as_uint(f);
    return (u + 0x7fffu + ((u >> 16) & 1u)) >> 16;   // RNE
}
__device__ __forceinline__ float bf_lo(unsigned u) { return __uint_as_float(u << 16); }
__device__ __forceinline__ float bf_hi(unsigned u) { return __uint_as_float(u & 0xffff0000u); }

// ---------------- prep: x->bf16 + Wt build + zero-row + per-node degree count ----------------
// Degrees counted with direct global atomics (random across 400 KB -> L2-handled);
// replaces the entire binify multisplit (epk intermediate deleted).
__global__ __launch_bounds__(256) void prep_kernel(const float* __restrict__ x,
                                                   const float* __restrict__ Wrel,
                                                   const float* __restrict__ Wroot,
                                                   const int* __restrict__ ei,
                                                   unsigned short* __restrict__ x_bf,
                                                   unsigned short* __restrict__ Wt,
                                                   int* __restrict__ deg) {
    int b = blockIdx.x;
    int t = threadIdx.x;
    if (b < CVT_X_BLOCKS) {
        size_t i = ((size_t)b * 256 + t) * 8;
        float4 v0 = *(const float4*)(x + i);
        float4 v1 = *(const float4*)(x + i + 4);
        uint4 p;
        p.x = f2bf(v0.x) | (f2bf(v0.y) << 16);
        p.y = f2bf(v0.z) | (f2bf(v0.w) << 16);
        p.z = f2bf(v1.x) | (f2bf(v1.y) << 16);
        p.w = f2bf(v1.z) | (f2bf(v1.w) << 16);
        *(uint4*)(x_bf + i) = p;
    } else if (b < CVT_X_BLOCKS + 128) {
        int c = b - CVT_X_BLOCKS;          // 0..127
        float v = (t < 128) ? Wrel[t * D + c] : Wroot[(t - 128) * D + c];
        Wt[c * 256 + t] = (unsigned short)f2bf(v);
    } else if (b == CVT_X_BLOCKS + 128) {
        // zero the padding row x_bf[N_NODES]: 128 shorts = 16 uint4
        if (t < 16) *(uint4*)(x_bf + (size_t)ZROW * D + t * 8) = make_uint4(0, 0, 0, 0);
    } else {
        int blk = b - (CVT_X_BLOCKS + 129);
        int base = blk * CHUNK;
#pragma unroll
        for (int i = 0; i < EPT; ++i) {
            int dst = ei[N_EDGES + base + i * 256 + t];
            atomicAdd(&deg[dst], 1);
        }
    }
}

// ---------------- rowstart: per-bucket scan of padded degrees + ZROW padding fill ----------------
// Bucket b owns fixed srcs region [b*PBK, (b+1)*PBK). Padding slots
// [rbeg+deg, rbeg+pdeg) are disjoint from scatter slots [rbeg, rbeg+deg),
// so they are filled here, BEFORE the scatter kernel.
__global__ __launch_bounds__(512) void rowstart_kernel(const int* __restrict__ deg,
                                                       int* __restrict__ rbeg,
                                                       int* __restrict__ rend,
                                                       int* __restrict__ rcur,
                                                       int* __restrict__ srcs) {
    __shared__ int s[512];
    int b = blockIdx.x;
    int t = threadIdx.x;
    int g = (b << 9) + t;
    int d = (g < N_NODES) ? deg[g] : 0;
    int pd = (d + 7) & ~7;
    s[t] = pd;
    __syncthreads();
    for (int off = 1; off < 512; off <<= 1) {
        int a = (t >= off) ? s[t - off] : 0;
        __syncthreads();
        s[t] += a;
        __syncthreads();
    }
    int st = b * PBK + s[t] - pd;
    if (g < 100352) { rbeg[g] = st; rend[g] = st + pd; rcur[g] = st; }
    for (int p = st + d; p < st + pd; ++p) srcs[p] = ZROW;
}

// ---------------- scatter: direct global-atomic placement ----------------
// srcs is 7.5 MB -> random 4B writes are L2/LLC-absorbed. No LDS, no barriers.
__global__ __launch_bounds__(256) void scatter_kernel(const int* __restrict__ ei,
                                                      int* __restrict__ rcur,
                                                      int* __restrict__ srcs) {
    int t = threadIdx.x;
    int base = blockIdx.x * CHUNK;
#pragma unroll
    for (int i = 0; i < EPT; ++i) {
        int e = base + i * 256 + t;
        int src = ei[e];
        int dst = ei[N_EDGES + e];
        int pos = atomicAdd(&rcur[dst], 1);
        srcs[pos] = src;
    }
}

// ---------------- FUSED gather + MFMA GEMM + BN stats (R8 verbatim — measured best) ----------------
// M=128, Af+Bf both in LDS (70 KB, 2 blocks/CU), plain launch bounds (VGPR 104).
// Occupancy experiments (R6/R7/R9) all regressed: fused gather BW does not scale
// with occupancy; this structure is the measured local optimum (~97 us).
__global__ __launch_bounds__(256) void fused_gemm(const unsigned short* __restrict__ x_bf,
                                                  const int* __restrict__ rbeg,
                                                  const int* __restrict__ rend,
                                                  const int* __restrict__ srcs,
                                                  const unsigned short* __restrict__ Wt,
                                                  const float* __restrict__ brel,
                                                  unsigned short* __restrict__ h_bf,
                                                  float* __restrict__ gsum,
                                                  float* __restrict__ gss) {
    __shared__ unsigned short Af[2048 * 8];   // 32 KB A tile, fragment-major, swizzled
    __shared__ unsigned short Bf[2048 * 8];   // 32 KB B fragments (one 128-k half at a time)
    __shared__ float sbias[128];
    __shared__ float SredS[4][128];
    __shared__ float SredQ[4][128];

    const int t = threadIdx.x;
    const int wave = t >> 6;
    const int lane = t & 63;
    const int quad = lane >> 4;
    const int l16 = lane & 15;
    const int blockRow = blockIdx.x * 128;

    if (t < 128) sbias[t] = brel[t];

    // ---- Phase 1: stage Bf = Wrel fragments (half 0)
#pragma unroll
    for (int f = t; f < 2048; f += 256) {
        int kcl = f >> 9;
        int ct = (f >> 6) & 7;
        int ln = f & 63;
        int col = ct * 16 + (ln & 15);
        int kb = kcl * 32 + ((ln >> 4) << 3);
        *(uint4*)&Bf[f * 8] = *(const uint4*)(Wt + col * 256 + kb);
    }

    // ---- Phase 2: gather this block's 128 aggregate rows into Af
    const unsigned short* xp = x_bf + l16 * 8;
#pragma unroll 1
    for (int g = 0; g < 8; ++g) {
        int r = wave * 32 + g * 4 + quad;        // local row 0..127
        int node = blockRow + r;                 // < 100352, rbeg/rend valid
        int e = rbeg[node];
        int end = rend[node];
        float a0 = 0.f, a1 = 0.f, a2 = 0.f, a3 = 0.f;
        float a4 = 0.f, a5 = 0.f, a6 = 0.f, a7 = 0.f;
        for (; e < end; e += 8) {
            int4 s0 = *(const int4*)(srcs + e);
            int4 s1 = *(const int4*)(srcs + e + 4);
            uint4 u0 = *(const uint4*)(xp + (size_t)s0.x * D);
            uint4 u1 = *(const uint4*)(xp + (size_t)s0.y * D);
            uint4 u2 = *(const uint4*)(xp + (size_t)s0.z * D);
            uint4 u3 = *(const uint4*)(xp + (size_t)s0.w * D);
            uint4 u4 = *(const uint4*)(xp + (size_t)s1.x * D);
            uint4 u5 = *(const uint4*)(xp + (size_t)s1.y * D);
            uint4 u6 = *(const uint4*)(xp + (size_t)s1.z * D);
            uint4 u7 = *(const uint4*)(xp + (size_t)s1.w * D);
            a0 += bf_lo(u0.x) + bf_lo(u1.x) + bf_lo(u2.x) + bf_lo(u3.x)
                + bf_lo(u4.x) + bf_lo(u5.x) + bf_lo(u6.x) + bf_lo(u7.x);
            a1 += bf_hi(u0.x) + bf_hi(u1.x) + bf_hi(u2.x) + bf_hi(u3.x)
                + bf_hi(u4.x) + bf_hi(u5.x) + bf_hi(u6.x) + bf_hi(u7.x);
            a2 += bf_lo(u0.y) + bf_lo(u1.y) + bf_lo(u2.y) + bf_lo(u3.y)
                + bf_lo(u4.y) + bf_lo(u5.y) + bf_lo(u6.y) + bf_lo(u7.y);
            a3 += bf_hi(u0.y) + bf_hi(u1.y) + bf_hi(u2.y) + bf_hi(u3.y)
                + bf_hi(u4.y) + bf_hi(u5.y) + bf_hi(u6.y) + bf_hi(u7.y);
            a4 += bf_lo(u0.z) + bf_lo(u1.z) + bf_lo(u2.z) + bf_lo(u3.z)
                + bf_lo(u4.z) + bf_lo(u5.z) + bf_lo(u6.z) + bf_lo(u7.z);
            a5 += bf_hi(u0.z) + bf_hi(u1.z) + bf_hi(u2.z) + bf_hi(u3.z)
                + bf_hi(u4.z) + bf_hi(u5.z) + bf_hi(u6.z) + bf_hi(u7.z);
            a6 += bf_lo(u0.w) + bf_lo(u1.w) + bf_lo(u2.w) + bf_lo(u3.w)
                + bf_lo(u4.w) + bf_lo(u5.w) + bf_lo(u6.w) + bf_lo(u7.w);
            a7 += bf_hi(u0.w) + bf_hi(u1.w) + bf_hi(u2.w) + bf_hi(u3.w)
                + bf_hi(u4.w) + bf_hi(u5.w) + bf_hi(u6.w) + bf_hi(u7.w);
        }
        uint4 w;
        w.x = f2bf(a0) | (f2bf(a1) << 16);
        w.y = f2bf(a2) | (f2bf(a3) << 16);
        w.z = f2bf(a4) | (f2bf(a5) << 16);
        w.w = f2bf(a6) | (f2bf(a7) << 16);
        int c = l16;
        int wf = ((r >> 5) << 3) + (((r >> 4) & 1) << 2) + (c >> 2);
        int L = ((c & 3) << 4) | ((r & 15) ^ (c & 3));
        *(uint4*)&Af[(wf * 64 + L) * 8] = w;
    }
    __syncthreads();   // Af + Bf(half0) complete

    f32x4 acc[2][8];
#pragma unroll
    for (int i = 0; i < 2; ++i)
#pragma unroll
        for (int j = 0; j < 8; ++j) acc[i][j] = (f32x4){0.f, 0.f, 0.f, 0.f};

    const int Lr = (quad << 4) | (l16 ^ quad);   // swizzled read index

    // ---- Phase 3: MFMA half-0 (aggr x Wrel), A and B from LDS, conflict-free
#pragma unroll
    for (int kcl = 0; kcl < 4; ++kcl) {
        bf16x8 af0 = *(const bf16x8*)&Af[(((wave << 3) + kcl) * 64 + Lr) * 8];          // rt=0
        bf16x8 af1 = *(const bf16x8*)&Af[(((wave << 3) + 4 + kcl) * 64 + Lr) * 8];      // rt=1
#pragma unroll
        for (int ct = 0; ct < 8; ++ct) {
            bf16x8 bfrag = *(const bf16x8*)&Bf[((kcl * 8 + ct) * 64 + lane) * 8];
            acc[0][ct] = __builtin_amdgcn_mfma_f32_16x16x32_bf16(af0, bfrag, acc[0][ct], 0, 0, 0);
            acc[1][ct] = __builtin_amdgcn_mfma_f32_16x16x32_bf16(af1, bfrag, acc[1][ct], 0, 0, 0);
        }
    }
    __syncthreads();   // all waves done reading Bf half-0

    // ---- restage Bf = Wroot fragments (half 1)
#pragma unroll
    for (int f = t; f < 2048; f += 256) {
        int kcl = f >> 9;
        int ct = (f >> 6) & 7;
        int ln = f & 63;
        int col = ct * 16 + (ln & 15);
        int kb = 128 + kcl * 32 + ((ln >> 4) << 3);
        *(uint4*)&Bf[f * 8] = *(const uint4*)(Wt + col * 256 + kb);
    }
    __syncthreads();

    // ---- Phase 4: MFMA half-1 (x x Wroot), A direct from global (coalesced)
    const int rowb = blockRow + wave * 32;
#pragma unroll
    for (int kcl = 0; kcl < 4; ++kcl) {
        const int k0 = kcl * 32 + quad * 8;
        bf16x8 af0 = *(const bf16x8*)(x_bf + (size_t)(rowb + l16) * D + k0);
        bf16x8 af1 = *(const bf16x8*)(x_bf + (size_t)(rowb + 16 + l16) * D + k0);
#pragma unroll
        for (int ct = 0; ct < 8; ++ct) {
            bf16x8 bfrag = *(const bf16x8*)&Bf[((kcl * 8 + ct) * 64 + lane) * 8];
            acc[0][ct] = __builtin_amdgcn_mfma_f32_16x16x32_bf16(af0, bfrag, acc[0][ct], 0, 0, 0);
            acc[1][ct] = __builtin_amdgcn_mfma_f32_16x16x32_bf16(af1, bfrag, acc[1][ct], 0, 0, 0);
        }
    }

    // ---- Epilogue: bias, h store (bf16), BN partial sums
    float csum[8], css[8];
#pragma unroll
    for (int ct = 0; ct < 8; ++ct) { csum[ct] = 0.f; css[ct] = 0.f; }

#pragma unroll
    for (int rt = 0; rt < 2; ++rt) {
#pragma unroll
        for (int ct = 0; ct < 8; ++ct) {
            int col = ct * 16 + l16;
            float bv = sbias[col];
#pragma unroll
            for (int reg = 0; reg < 4; ++reg) {
                int row = blockRow + wave * 32 + rt * 16 + quad * 4 + reg;
                if (row < N_NODES) {
                    float v = acc[rt][ct][reg] + bv;
                    h_bf[(size_t)row * D + col] = (unsigned short)f2bf(v);
                    csum[ct] += v;
                    css[ct] += v * v;
                }
            }
        }
    }
#pragma unroll
    for (int ct = 0; ct < 8; ++ct) {
        float s = csum[ct], q = css[ct];
        s += __shfl_xor(s, 16);
        s += __shfl_xor(s, 32);
        q += __shfl_xor(q, 16);
        q += __shfl_xor(q, 32);
        if (quad == 0) {
            SredS[wave][ct * 16 + l16] = s;
            SredQ[wave][ct * 16 + l16] = q;
        }
    }
    __syncthreads();
    if (t < 128) {
        float s = SredS[0][t] + SredS[1][t] + SredS[2][t] + SredS[3][t];
        float q = SredQ[0][t] + SredQ[1][t] + SredQ[2][t] + SredQ[3][t];
        unsafeAtomicAdd(&gsum[t], s);
        unsafeAtomicAdd(&gss[t], q);
    }
}

// ---------------- normalize + relu: read h_bf, write f32 out ----------------
__global__ __launch_bounds__(256) void norm_kernel(const unsigned short* __restrict__ h_bf,
                                                   float* __restrict__ out,
                                                   const float* __restrict__ gsum,
                                                   const float* __restrict__ gss,
                                                   const float* __restrict__ gamma,
                                                   const float* __restrict__ beta) {
    __shared__ float sscale[128];
    __shared__ float sshift[128];
    int t = threadIdx.x;
    if (t < 128) {
        const float inv_n = 1.0f / (float)N_NODES;
        float mean = gsum[t] * inv_n;
        float var = gss[t] * inv_n - mean * mean;
        float rs = rsqrtf(var + 1e-5f);
        float sc = gamma[t] * rs;
        sscale[t] = sc;
        sshift[t] = beta[t] - mean * sc;
    }
    __syncthreads();
    size_t e = ((size_t)blockIdx.x * 256 + t) * 4;
    if (e >= (size_t)N_NODES * D) return;
    int c = (int)(e & 127);
    uint2 u = *(const uint2*)(h_bf + e);
    float4 v;
    v.x = fmaxf(bf_lo(u.x) * sscale[c + 0] + sshift[c + 0], 0.f);
    v.y = fmaxf(bf_hi(u.x) * sscale[c + 1] + sshift[c + 1], 0.f);
    v.z = fmaxf(bf_lo(u.y) * sscale[c + 2] + sshift[c + 2], 0.f);
    v.w = fmaxf(bf_hi(u.y) * sscale[c + 3] + sshift[c + 3], 0.f);
    *(float4*)(out + e) = v;
}

extern "C" void kernel_launch(void* const* d_in, const int* in_sizes, int n_in,
                              void* d_out, int out_size, void* d_ws, size_t ws_size,
                              hipStream_t stream) {
    const float* x     = (const float*)d_in[0];
    const int*   ei    = (const int*)d_in[1];
    const float* Wroot = (const float*)d_in[2];
    const float* Wrel  = (const float*)d_in[3];
    const float* brel  = (const float*)d_in[4];
    const float* gamma = (const float*)d_in[5];
    const float* beta  = (const float*)d_in[6];
    float* out = (float*)d_out;

    // workspace layout: no epk anymore. srcs lives through fused_gemm.
    unsigned short* h_bf = (unsigned short*)d_ws;                    // 25.6 MB
    unsigned short* x_bf = h_bf + (size_t)N_NODES * D;               // (N+1)*D
    unsigned short* Wt   = x_bf + (size_t)(N_NODES + 1) * D;         // 128*256
    float* gsum  = (float*)(Wt + 128 * 256);                    // 128 ─┐
    float* gss   = gsum + 128;                                  // 128  │ one memset
    int* deg     = (int*)(gss + 128);                           // 100352 ─┘
    int* rbeg    = deg + 100352;                                // 100352
    int* rend    = rbeg + 100352;                               // 100352
    int* rcur    = rend + 100352;                               // 100352
    int* srcs    = rcur + 100352;                               // 196*PBK (10.4 MB, padded)

    // zero gsum+gss+deg in one contiguous memset
    hipMemsetAsync(gsum, 0, (256 + 100352) * sizeof(int), stream);

    prep_kernel<<<CVT_X_BLOCKS + 129 + BIN_BLOCKS, 256, 0, stream>>>(
        x, Wrel, Wroot, ei, x_bf, Wt, deg);
    rowstart_kernel<<<NB, 512, 0, stream>>>(deg, rbeg, rend, rcur, srcs);
    scatter_kernel<<<BIN_BLOCKS, 256, 0, stream>>>(ei, rcur, srcs);
    fused_gemm<<<(N_NODES + 127) / 128, 256, 0, stream>>>(
        x_bf, rbeg, rend, srcs, Wt, brel, h_bf, gsum, gss);
    norm_kernel<<<12500, 256, 0, stream>>>(h_bf, out, gsum, gss, gamma, beta);
}

// Round 11
// 248.734 us; speedup vs baseline: 1.5895x; 1.5895x over previous
//
#include <hip/hip_runtime.h>

#define N_NODES 100000
#define N_EDGES 1600000
#define D 128
#define NB 196              // buckets of 512 nodes: 196*512 = 100352 >= N_NODES
#define EPT 10              // edges per thread in binning
#define CHUNK 2560          // 256 threads * EPT
#define BIN_BLOCKS 625      // 625 * 2560 = 1,600,000 exactly
#define CVT_X_BLOCKS 6250   // 6250*256*8 = 12.8M elements
#define ZROW N_NODES        // index of the zeroed padding row in x_bf
#define PBK 13312           // per-bucket fixed region (max ~8600 edges + 512*7 pad)

typedef __bf16 bf16x8 __attribute__((ext_vector_type(8)));
typedef float f32x4 __attribute__((ext_vector_type(4)));

__device__ __forceinline__ unsigned f2bf(float f) {
    unsigned u = __float_as_uint(f);
    return (u + 0x7fffu + ((u >> 16) & 1u)) >> 16;   // RNE
}
__device__ __forceinline__ float bf_lo(unsigned u) { return __uint_as_float(u << 16); }
__device__ __forceinline__ float bf_hi(unsigned u) { return __uint_as_float(u & 0xffff0000u); }

// ---------------- MERGED prep + binify fat kernel ----------------
// Branch 0 (blocks 0..BIN_BLOCKS): binify — block-local multisplit of CHUNK edges
//   into bucket-contiguous epk codes. Needs only ei + bcur zeroed (memset), so it
//   runs CONCURRENTLY with the x-conversion branch (serial sum -> max).
//   bcur[b] is an OFFSET within bucket b's fixed region (base b*PBK).
// Branch 1 (next CVT_X_BLOCKS): x -> bf16 row-major.
// Branch 2 (next 128): Wt build. Branch 3 (last): zero row.
__global__ __launch_bounds__(256) void prep_kernel(const float* __restrict__ x,
                                                   const float* __restrict__ Wrel,
                                                   const float* __restrict__ Wroot,
                                                   const int* __restrict__ ei,
                                                   unsigned short* __restrict__ x_bf,
                                                   unsigned short* __restrict__ Wt,
                                                   int* __restrict__ bcur,
                                                   unsigned* __restrict__ epk) {
    __shared__ int lhist[256];
    __shared__ int lstart[256];
    __shared__ int lfill[256];
    __shared__ int gbase[256];
    __shared__ uint2 stage[CHUNK];

    int b = blockIdx.x;
    int t = threadIdx.x;
    if (b < BIN_BLOCKS) {
        int base = b * CHUNK;
        lhist[t] = 0;
        lfill[t] = 0;
        __syncthreads();

        int src[EPT], dst[EPT];
#pragma unroll
        for (int i = 0; i < EPT; ++i) {
            int e = base + i * 256 + t;
            src[i] = ei[e];
            dst[i] = ei[N_EDGES + e];
            atomicAdd(&lhist[dst[i] >> 9], 1);
        }
        __syncthreads();

        int v = lhist[t];
        lstart[t] = v;
        __syncthreads();
        for (int off = 1; off < 256; off <<= 1) {
            int a = (t >= off) ? lstart[t - off] : 0;
            __syncthreads();
            lstart[t] += a;
            __syncthreads();
        }
        int excl = lstart[t] - v;
        if (t < NB && v > 0) gbase[t] = t * PBK + atomicAdd(&bcur[t], v);
        __syncthreads();
        lstart[t] = excl;
        __syncthreads();

#pragma unroll
        for (int i = 0; i < EPT; ++i) {
            int bb = dst[i] >> 9;
            int lp = atomicAdd(&lfill[bb], 1);
            stage[lstart[bb] + lp] = make_uint2((unsigned)src[i], (unsigned)dst[i]);
        }
        __syncthreads();

        for (int i = t; i < CHUNK; i += 256) {
            uint2 p = stage[i];
            int bb = (int)(p.y >> 9);
            unsigned code = p.x | ((p.y & 511u) << 17);
            epk[gbase[bb] + (i - lstart[bb])] = code;
        }
    } else if (b < BIN_BLOCKS + CVT_X_BLOCKS) {
        size_t i = ((size_t)(b - BIN_BLOCKS) * 256 + t) * 8;
        float4 v0 = *(const float4*)(x + i);
        float4 v1 = *(const float4*)(x + i + 4);
        uint4 p;
        p.x = f2bf(v0.x) | (f2bf(v0.y) << 16);
        p.y = f2bf(v0.z) | (f2bf(v0.w) << 16);
        p.z = f2bf(v1.x) | (f2bf(v1.y) << 16);
        p.w = f2bf(v1.z) | (f2bf(v1.w) << 16);
        *(uint4*)(x_bf + i) = p;
    } else if (b < BIN_BLOCKS + CVT_X_BLOCKS + 128) {
        int c = b - (BIN_BLOCKS + CVT_X_BLOCKS);   // 0..127
        float v = (t < 128) ? Wrel[t * D + c] : Wroot[(t - 128) * D + c];
        Wt[c * 256 + t] = (unsigned short)f2bf(v);
    } else {
        // zero the padding row x_bf[N_NODES]: 128 shorts = 16 uint4
        if (t < 16) *(uint4*)(x_bf + (size_t)ZROW * D + t * 8) = make_uint4(0, 0, 0, 0);
    }
}

// ---------------- place: 512 thr, 1 node/thread; padded scan -> rbeg/rend, srcs ----------------
// pbeg = b*PBK (fixed), pend = b*PBK + bcur[b] (offset cursor after binify).
__global__ __launch_bounds__(512) void place_kernel(const unsigned* __restrict__ epk,
                                                    const int* __restrict__ bcur,
                                                    int* __restrict__ rbeg,
                                                    int* __restrict__ rend,
                                                    int* __restrict__ srcs) {
    __shared__ int cnt[512];
    __shared__ int s[512];
    __shared__ int cursor[512];
    int b = blockIdx.x;
    int t = threadIdx.x;
    int R = b * PBK;
    int pbeg = R;
    int pend = R + bcur[b];

    cnt[t] = 0;
    __syncthreads();
    for (int i = pbeg + t; i < pend; i += 512)
        atomicAdd(&cnt[epk[i] >> 17], 1);
    __syncthreads();

    // inclusive scan of padded counts -> exclusive offsets
    int v = (cnt[t] + 7) & ~7;
    s[t] = v;
    __syncthreads();
    for (int off = 1; off < 512; off <<= 1) {
        int a = (t >= off) ? s[t - off] : 0;
        __syncthreads();
        s[t] += a;
        __syncthreads();
    }
    int st = R + s[t] - v;
    int g = (b << 9) + t;
    if (g < 100352) { rbeg[g] = st; rend[g] = st + v; }
    cursor[t] = st;
    __syncthreads();

    for (int i = pbeg + t; i < pend; i += 512) {
        unsigned code = epk[i];
        int pos = atomicAdd(&cursor[code >> 17], 1);
        srcs[pos] = (int)(code & 0x1FFFFu);
    }
    __syncthreads();

    // fill padding slots with the zero-row sentinel
    int endp = st + v;
    for (int p = cursor[t]; p < endp; ++p) srcs[p] = ZROW;
}

// ---------------- FUSED gather + MFMA GEMM + BN stats (R8 verbatim — measured best) ----------------
// M=128, Af+Bf both in LDS (70 KB, 2 blocks/CU), plain launch bounds (VGPR 104).
// Occupancy experiments (R6/R7/R9) all regressed: fused gather BW does not scale
// with occupancy; this structure is the measured local optimum (~97 us).
__global__ __launch_bounds__(256) void fused_gemm(const unsigned short* __restrict__ x_bf,
                                                  const int* __restrict__ rbeg,
                                                  const int* __restrict__ rend,
                                                  const int* __restrict__ srcs,
                                                  const unsigned short* __restrict__ Wt,
                                                  const float* __restrict__ brel,
                                                  unsigned short* __restrict__ h_bf,
                                                  float* __restrict__ gsum,
                                                  float* __restrict__ gss) {
    __shared__ unsigned short Af[2048 * 8];   // 32 KB A tile, fragment-major, swizzled
    __shared__ unsigned short Bf[2048 * 8];   // 32 KB B fragments (one 128-k half at a time)
    __shared__ float sbias[128];
    __shared__ float SredS[4][128];
    __shared__ float SredQ[4][128];

    const int t = threadIdx.x;
    const int wave = t >> 6;
    const int lane = t & 63;
    const int quad = lane >> 4;
    const int l16 = lane & 15;
    const int blockRow = blockIdx.x * 128;

    if (t < 128) sbias[t] = brel[t];

    // ---- Phase 1: stage Bf = Wrel fragments (half 0)
#pragma unroll
    for (int f = t; f < 2048; f += 256) {
        int kcl = f >> 9;
        int ct = (f >> 6) & 7;
        int ln = f & 63;
        int col = ct * 16 + (ln & 15);
        int kb = kcl * 32 + ((ln >> 4) << 3);
        *(uint4*)&Bf[f * 8] = *(const uint4*)(Wt + col * 256 + kb);
    }

    // ---- Phase 2: gather this block's 128 aggregate rows into Af
    const unsigned short* xp = x_bf + l16 * 8;
#pragma unroll 1
    for (int g = 0; g < 8; ++g) {
        int r = wave * 32 + g * 4 + quad;        // local row 0..127
        int node = blockRow + r;                 // < 100352, rbeg/rend valid
        int e = rbeg[node];
        int end = rend[node];
        float a0 = 0.f, a1 = 0.f, a2 = 0.f, a3 = 0.f;
        float a4 = 0.f, a5 = 0.f, a6 = 0.f, a7 = 0.f;
        for (; e < end; e += 8) {
            int4 s0 = *(const int4*)(srcs + e);
            int4 s1 = *(const int4*)(srcs + e + 4);
            uint4 u0 = *(const uint4*)(xp + (size_t)s0.x * D);
            uint4 u1 = *(const uint4*)(xp + (size_t)s0.y * D);
            uint4 u2 = *(const uint4*)(xp + (size_t)s0.z * D);
            uint4 u3 = *(const uint4*)(xp + (size_t)s0.w * D);
            uint4 u4 = *(const uint4*)(xp + (size_t)s1.x * D);
            uint4 u5 = *(const uint4*)(xp + (size_t)s1.y * D);
            uint4 u6 = *(const uint4*)(xp + (size_t)s1.z * D);
            uint4 u7 = *(const uint4*)(xp + (size_t)s1.w * D);
            a0 += bf_lo(u0.x) + bf_lo(u1.x) + bf_lo(u2.x) + bf_lo(u3.x)
                + bf_lo(u4.x) + bf_lo(u5.x) + bf_lo(u6.x) + bf_lo(u7.x);
            a1 += bf_hi(u0.x) + bf_hi(u1.x) + bf_hi(u2.x) + bf_hi(u3.x)
                + bf_hi(u4.x) + bf_hi(u5.x) + bf_hi(u6.x) + bf_hi(u7.x);
            a2 += bf_lo(u0.y) + bf_lo(u1.y) + bf_lo(u2.y) + bf_lo(u3.y)
                + bf_lo(u4.y) + bf_lo(u5.y) + bf_lo(u6.y) + bf_lo(u7.y);
            a3 += bf_hi(u0.y) + bf_hi(u1.y) + bf_hi(u2.y) + bf_hi(u3.y)
                + bf_hi(u4.y) + bf_hi(u5.y) + bf_hi(u6.y) + bf_hi(u7.y);
            a4 += bf_lo(u0.z) + bf_lo(u1.z) + bf_lo(u2.z) + bf_lo(u3.z)
                + bf_lo(u4.z) + bf_lo(u5.z) + bf_lo(u6.z) + bf_lo(u7.z);
            a5 += bf_hi(u0.z) + bf_hi(u1.z) + bf_hi(u2.z) + bf_hi(u3.z)
                + bf_hi(u4.z) + bf_hi(u5.z) + bf_hi(u6.z) + bf_hi(u7.z);
            a6 += bf_lo(u0.w) + bf_lo(u1.w) + bf_lo(u2.w) + bf_lo(u3.w)
                + bf_lo(u4.w) + bf_lo(u5.w) + bf_lo(u6.w) + bf_lo(u7.w);
            a7 += bf_hi(u0.w) + bf_hi(u1.w) + bf_hi(u2.w) + bf_hi(u3.w)
                + bf_hi(u4.w) + bf_hi(u5.w) + bf_hi(u6.w) + bf_hi(u7.w);
        }
        uint4 w;
        w.x = f2bf(a0) | (f2bf(a1) << 16);
        w.y = f2bf(a2) | (f2bf(a3) << 16);
        w.z = f2bf(a4) | (f2bf(a5) << 16);
        w.w = f2bf(a6) | (f2bf(a7) << 16);
        int c = l16;
        int wf = ((r >> 5) << 3) + (((r >> 4) & 1) << 2) + (c >> 2);
        int L = ((c & 3) << 4) | ((r & 15) ^ (c & 3));
        *(uint4*)&Af[(wf * 64 + L) * 8] = w;
    }
    __syncthreads();   // Af + Bf(half0) complete

    f32x4 acc[2][8];
#pragma unroll
    for (int i = 0; i < 2; ++i)
#pragma unroll
        for (int j = 0; j < 8; ++j) acc[i][j] = (f32x4){0.f, 0.f, 0.f, 0.f};

    const int Lr = (quad << 4) | (l16 ^ quad);   // swizzled read index

    // ---- Phase 3: MFMA half-0 (aggr x Wrel), A and B from LDS, conflict-free
#pragma unroll
    for (int kcl = 0; kcl < 4; ++kcl) {
        bf16x8 af0 = *(const bf16x8*)&Af[(((wave << 3) + kcl) * 64 + Lr) * 8];          // rt=0
        bf16x8 af1 = *(const bf16x8*)&Af[(((wave << 3) + 4 + kcl) * 64 + Lr) * 8];      // rt=1
#pragma unroll
        for (int ct = 0; ct < 8; ++ct) {
            bf16x8 bfrag = *(const bf16x8*)&Bf[((kcl * 8 + ct) * 64 + lane) * 8];
            acc[0][ct] = __builtin_amdgcn_mfma_f32_16x16x32_bf16(af0, bfrag, acc[0][ct], 0, 0, 0);
            acc[1][ct] = __builtin_amdgcn_mfma_f32_16x16x32_bf16(af1, bfrag, acc[1][ct], 0, 0, 0);
        }
    }
    __syncthreads();   // all waves done reading Bf half-0

    // ---- restage Bf = Wroot fragments (half 1)
#pragma unroll
    for (int f = t; f < 2048; f += 256) {
        int kcl = f >> 9;
        int ct = (f >> 6) & 7;
        int ln = f & 63;
        int col = ct * 16 + (ln & 15);
        int kb = 128 + kcl * 32 + ((ln >> 4) << 3);
        *(uint4*)&Bf[f * 8] = *(const uint4*)(Wt + col * 256 + kb);
    }
    __syncthreads();

    // ---- Phase 4: MFMA half-1 (x x Wroot), A direct from global (coalesced)
    const int rowb = blockRow + wave * 32;
#pragma unroll
    for (int kcl = 0; kcl < 4; ++kcl) {
        const int k0 = kcl * 32 + quad * 8;
        bf16x8 af0 = *(const bf16x8*)(x_bf + (size_t)(rowb + l16) * D + k0);
        bf16x8 af1 = *(const bf16x8*)(x_bf + (size_t)(rowb + 16 + l16) * D + k0);
#pragma unroll
        for (int ct = 0; ct < 8; ++ct) {
            bf16x8 bfrag = *(const bf16x8*)&Bf[((kcl * 8 + ct) * 64 + lane) * 8];
            acc[0][ct] = __builtin_amdgcn_mfma_f32_16x16x32_bf16(af0, bfrag, acc[0][ct], 0, 0, 0);
            acc[1][ct] = __builtin_amdgcn_mfma_f32_16x16x32_bf16(af1, bfrag, acc[1][ct], 0, 0, 0);
        }
    }

    // ---- Epilogue: bias, h store (bf16), BN partial sums
    float csum[8], css[8];
#pragma unroll
    for (int ct = 0; ct < 8; ++ct) { csum[ct] = 0.f; css[ct] = 0.f; }

#pragma unroll
    for (int rt = 0; rt < 2; ++rt) {
#pragma unroll
        for (int ct = 0; ct < 8; ++ct) {
            int col = ct * 16 + l16;
            float bv = sbias[col];
#pragma unroll
            for (int reg = 0; reg < 4; ++reg) {
                int row = blockRow + wave * 32 + rt * 16 + quad * 4 + reg;
                if (row < N_NODES) {
                    float v = acc[rt][ct][reg] + bv;
                    h_bf[(size_t)row * D + col] = (unsigned short)f2bf(v);
                    csum[ct] += v;
                    css[ct] += v * v;
                }
            }
        }
    }
#pragma unroll
    for (int ct = 0; ct < 8; ++ct) {
        float s = csum[ct], q = css[ct];
        s += __shfl_xor(s, 16);
        s += __shfl_xor(s, 32);
        q += __shfl_xor(q, 16);
        q += __shfl_xor(q, 32);
        if (quad == 0) {
            SredS[wave][ct * 16 + l16] = s;
            SredQ[wave][ct * 16 + l16] = q;
        }
    }
    __syncthreads();
    if (t < 128) {
        float s = SredS[0][t] + SredS[1][t] + SredS[2][t] + SredS[3][t];
        float q = SredQ[0][t] + SredQ[1][t] + SredQ[2][t] + SredQ[3][t];
        unsafeAtomicAdd(&gsum[t], s);
        unsafeAtomicAdd(&gss[t], q);
    }
}

// ---------------- normalize + relu: 8 elems/thread (uint4 read, 2x float4 write) ----------------
__global__ __launch_bounds__(256) void norm_kernel(const unsigned short* __restrict__ h_bf,
                                                   float* __restrict__ out,
                                                   const float* __restrict__ gsum,
                                                   const float* __restrict__ gss,
                                                   const float* __restrict__ gamma,
                                                   const float* __restrict__ beta) {
    __shared__ float sscale[128];
    __shared__ float sshift[128];
    int t = threadIdx.x;
    if (t < 128) {
        const float inv_n = 1.0f / (float)N_NODES;
        float mean = gsum[t] * inv_n;
        float var = gss[t] * inv_n - mean * mean;
        float rs = rsqrtf(var + 1e-5f);
        float sc = gamma[t] * rs;
        sscale[t] = sc;
        sshift[t] = beta[t] - mean * sc;
    }
    __syncthreads();
    size_t e = ((size_t)blockIdx.x * 256 + t) * 8;
    if (e >= (size_t)N_NODES * D) return;
    int c = (int)(e & 127);
    uint4 u = *(const uint4*)(h_bf + e);
    float4 v0, v1;
    v0.x = fmaxf(bf_lo(u.x) * sscale[c + 0] + sshift[c + 0], 0.f);
    v0.y = fmaxf(bf_hi(u.x) * sscale[c + 1] + sshift[c + 1], 0.f);
    v0.z = fmaxf(bf_lo(u.y) * sscale[c + 2] + sshift[c + 2], 0.f);
    v0.w = fmaxf(bf_hi(u.y) * sscale[c + 3] + sshift[c + 3], 0.f);
    v1.x = fmaxf(bf_lo(u.z) * sscale[c + 4] + sshift[c + 4], 0.f);
    v1.y = fmaxf(bf_hi(u.z) * sscale[c + 5] + sshift[c + 5], 0.f);
    v1.z = fmaxf(bf_lo(u.w) * sscale[c + 6] + sshift[c + 6], 0.f);
    v1.w = fmaxf(bf_hi(u.w) * sscale[c + 7] + sshift[c + 7], 0.f);
    *(float4*)(out + e) = v0;
    *(float4*)(out + e + 4) = v1;
}

extern "C" void kernel_launch(void* const* d_in, const int* in_sizes, int n_in,
                              void* d_out, int out_size, void* d_ws, size_t ws_size,
                              hipStream_t stream) {
    const float* x     = (const float*)d_in[0];
    const int*   ei    = (const int*)d_in[1];
    const float* Wroot = (const float*)d_in[2];
    const float* Wrel  = (const float*)d_in[3];
    const float* brel  = (const float*)d_in[4];
    const float* gamma = (const float*)d_in[5];
    const float* beta  = (const float*)d_in[6];
    float* out = (float*)d_out;

    // workspace layout: epk (10.4 MB, dead after place) ALIASES h_bf (25.6 MB,
    // written only by fused_gemm which runs after place). srcs stays live
    // through fused_gemm so it gets its own region.
    unsigned short* h_bf = (unsigned short*)d_ws;                    // 25.6 MB
    unsigned* epk = (unsigned*)d_ws;                                 // 196*PBK (10.4 MB, alias)
    unsigned short* x_bf = h_bf + (size_t)N_NODES * D;               // (N+1)*D
    unsigned short* Wt   = x_bf + (size_t)(N_NODES + 1) * D;         // 128*256
    float* gsum  = (float*)(Wt + 128 * 256);                    // 128 ─┐
    float* gss   = gsum + 128;                                  // 128  │ one memset
    int* bcur    = (int*)(gss + 128);                           // 256 ─┘ (offsets, zeroed)
    int* rbeg    = bcur + 256;                                  // 100352
    int* rend    = rbeg + 100352;                               // 100352
    int* srcs    = rend + 100352;                               // 196*PBK (10.4 MB, padded)

    // zero gsum + gss + bcur in one contiguous memset (bcur = per-bucket OFFSETS)
    hipMemsetAsync(gsum, 0, 512 * sizeof(int), stream);

    prep_kernel<<<BIN_BLOCKS + CVT_X_BLOCKS + 129, 256, 0, stream>>>(
        x, Wrel, Wroot, ei, x_bf, Wt, bcur, epk);
    place_kernel<<<NB, 512, 0, stream>>>(epk, bcur, rbeg, rend, srcs);
    fused_gemm<<<(N_NODES + 127) / 128, 256, 0, stream>>>(
        x_bf, rbeg, rend, srcs, Wt, brel, h_bf, gsum, gss);
    norm_kernel<<<6250, 256, 0, stream>>>(h_bf, out, gsum, gss, gamma, beta);
}